// Round 13
// baseline (188.952 us; speedup 1.0000x reference)
//
#include <hip/hip_runtime.h>
#include <math.h>

// Problem constants (B, N, L, D) from the reference setup_inputs().
#define BSZ 64
#define NN  128
#define LL  64
#define DD  768
#define NEGV (-9e9f)

#define TQ (BSZ * NN * DD / 4)   // text float4 count  = 1572864
#define IQ (BSZ * LL * DD / 4)   // image float4 count =  786432
#define PREP_BLOCKS ((TQ + IQ) / 256)   // 9216
#define TR_BLOCKS   (BSZ * 6)           // 384: (b, dc) transpose blocks

typedef _Float16 f16x8 __attribute__((ext_vector_type(8)));  // 8 f16 = 4 VGPRs
typedef __attribute__((ext_vector_type(4))) float f32x4;     // MFMA 16x16 accum

// async 16B global -> LDS (dest = wave-uniform base + lane*16)
__device__ __forceinline__ void gl_lds16(const void* g, void* l) {
    __builtin_amdgcn_global_load_lds(
        (const __attribute__((address_space(1))) void*)g,
        (__attribute__((address_space(3))) void*)l, 16, 0, 0);
}

__device__ __forceinline__ ushort4 cvt4(float4 x) {
    _Float16 h0 = (_Float16)x.x, h1 = (_Float16)x.y;
    _Float16 h2 = (_Float16)x.z, h3 = (_Float16)x.w;
    ushort4 o;
    o.x = __builtin_bit_cast(unsigned short, h0);
    o.y = __builtin_bit_cast(unsigned short, h1);
    o.z = __builtin_bit_cast(unsigned short, h2);
    o.w = __builtin_bit_cast(unsigned short, h3);
    return o;
}

// ---------------------------------------------------------------------------
// Kernel 0 (R13): fp32 -> fp16 (RTN) prep, with k_tr FUSED as extra blocks.
// Blocks [0, 9216): linear convert (text->A, img->B), as before.
// Blocks [9216, 9600): read img fp32 directly, convert (same RTN ops ->
// bit-identical to B), LDS-transpose, write BT[b][d][l]. Independent of the
// prep blocks (reads the INPUT, not B) -> no cross-block ordering needed.
// Saves one launch + a 12.6 MB fp16 re-read vs the separate k_tr.
// ---------------------------------------------------------------------------
__global__ __launch_bounds__(256) void k_prep(
    const float4* __restrict__ t4, const float4* __restrict__ g4,
    ushort4* __restrict__ A, ushort4* __restrict__ B,
    unsigned short* __restrict__ BT)
{
    __shared__ unsigned short Ls[64][136];   // transpose staging (17.4 KB)
    const int bid = blockIdx.x;

    if (bid < PREP_BLOCKS) {
        int id = bid * 256 + threadIdx.x;
        const float4* src; ushort4* dst; int idx;
        if (id < TQ) { src = t4; dst = A; idx = id; }
        else         { src = g4; dst = B; idx = id - TQ; }
        dst[idx] = cvt4(src[idx]);
        return;
    }

    // transpose blocks: (b, dc) over img fp32 [b][l][dc*128 .. +128)
    const int bid2 = bid - PREP_BLOCKS;
    const int b  = bid2 / 6;
    const int dc = bid2 % 6;
    const float4* gb = g4 + ((size_t)b * LL * DD + dc * 128) / 4;

#pragma unroll
    for (int rep = 0; rep < 8; rep++) {
        int idx = rep * 256 + threadIdx.x;    // 0..2047
        int l = idx >> 5, f4i = idx & 31;     // 64 rows x 32 float4 (=128 d)
        float4 x = gb[(size_t)l * (DD / 4) + f4i];
        *(ushort4*)(&Ls[l][f4i * 4]) = cvt4(x);
    }
    __syncthreads();

    unsigned short* BTb = BT + (size_t)b * DD * LL + (size_t)dc * 128 * LL;
#pragma unroll
    for (int rep = 0; rep < 4; rep++) {
        int idx = rep * 256 + threadIdx.x;    // 0..1023
        int d = idx >> 3, l0 = (idx & 7) * 8;
        ushort4 lo, hi;
        lo.x = Ls[l0 + 0][d]; lo.y = Ls[l0 + 1][d];
        lo.z = Ls[l0 + 2][d]; lo.w = Ls[l0 + 3][d];
        hi.x = Ls[l0 + 4][d]; hi.y = Ls[l0 + 5][d];
        hi.z = Ls[l0 + 6][d]; hi.w = Ls[l0 + 7][d];
        *(ushort4*)(BTb + (size_t)d * LL + l0)     = lo;
        *(ushort4*)(BTb + (size_t)d * LL + l0 + 4) = hi;
    }
}

// ---------------------------------------------------------------------------
// Stage one 32 KB chunk (A: 128 rows x 64 k f16, B: 128 rows x 64 k) into LDS.
// LDS slot for (r, k8): r*8 + (k8 ^ (r&7)), 16B per slot (XOR bank swizzle).
// [Session ledger: this BK=64/12-chunk structure = 87 us verified (R2/R8/R12).
//  BK=32: 160. 512-thr tiles: VGPR spill x3. In-reg shfl epilogue: 180.
//  Source-level pipelining on 2-phase: null per guide m131-m141. FROZEN.]
// ---------------------------------------------------------------------------
__device__ __forceinline__ void stage_chunk(
    const unsigned short* __restrict__ pa, const unsigned short* __restrict__ pb,
    int k0, char* buf, int wave, int lane)
{
    int rsub = lane >> 3;     // 0..7
    int k8s  = lane & 7;
#pragma unroll
    for (int c = 0; c < 4; c++) {
        int r  = c * 32 + wave * 8 + rsub;
        int k8 = k8s ^ (r & 7);
        gl_lds16(pa + (size_t)r * DD + k0 + k8 * 8, buf + c * 4096 + wave * 1024);
        gl_lds16(pb + (size_t)r * DD + k0 + k8 * 8, buf + 16384 + c * 4096 + wave * 1024);
    }
}

// ---------------------------------------------------------------------------
// Kernel 1: one block per (i, jj) where jj covers j = {2jj, 2jj+1}.
// C[128][128] = text[i] @ [image[j0]; image[j1]]^T, single-pass fp16 MFMA,
// LDS-staged via global_load_lds, double-buffered, 12 chunks of BK=64.
// Measured (R2/R8/R12): 87 us, MfmaUtil 24%, occ 20%, VGPR 88. FROZEN.
// ---------------------------------------------------------------------------
__global__ __launch_bounds__(256, 2) void k_scores(
    const unsigned short* __restrict__ A, const unsigned short* __restrict__ B,
    const int* __restrict__ tmask, const int* __restrict__ imask,
    float* __restrict__ S, unsigned short* __restrict__ Wh)
{
    union SmemU {
        char  stage[2][32768];     // [buf][A 16KB | B 16KB]
        float Cs[NN][129];         // 66 KB epilogue tile (stride 129: 2-way free)
    };
    __shared__ SmemU u;
    __shared__ float tmi[NN];
    __shared__ float imj[NN];      // 128 cols = two j's
    __shared__ float rowred[256];
    __shared__ float colred[NN];
    __shared__ float rowm[256], rowsm[256];          // phase-1 row stats stash
    __shared__ float colm[256], colp1[256], colp2[256];  // phase-2 partials

    // 4x4 block-group swizzle for L2 locality (~1.6 MB working set / group)
    const int bid = blockIdx.x;
    const int grp = bid >> 4, idx = bid & 15;
    const int i  = (grp >> 3) * 4 + (idx >> 2);   // 0..63
    const int jj = (grp & 7) * 4 + (idx & 3);     // 0..31
    const int j0 = jj * 2;

    const int tid  = threadIdx.x;
    const int wave = tid >> 6;
    const int lane = tid & 63;
    const int quad = lane >> 4;
    const int l15  = lane & 15;
    const int rh   = wave & 1;     // row half (64 rows)
    const int ch   = wave >> 1;    // col half (64 cols)

    if (tid < NN) {
        tmi[tid] = tmask[i * NN + tid] ? 1.f : 0.f;
        imj[tid] = imask[j0 * LL + tid] ? 1.f : 0.f;   // two j's contiguous
    }

    const unsigned short* pa = A + (size_t)i * NN * DD;
    const unsigned short* pb = B + (size_t)j0 * LL * DD;

    f32x4 acc[4][4];
    const f32x4 zf = {0.f, 0.f, 0.f, 0.f};
#pragma unroll
    for (int tr = 0; tr < 4; tr++)
#pragma unroll
        for (int tc = 0; tc < 4; tc++) acc[tr][tc] = zf;

    stage_chunk(pa, pb, 0, u.stage[0], wave, lane);
    __syncthreads();

    for (int c = 0; c < 12; c++) {
        if (c + 1 < 12)
            stage_chunk(pa, pb, (c + 1) << 6, u.stage[(c + 1) & 1], wave, lane);
        const char* Ab = u.stage[c & 1];
        const char* Bb = Ab + 16384;
#pragma unroll
        for (int s = 0; s < 2; s++) {
            int k8q = s * 4 + quad;
            int sw  = k8q ^ (l15 & 7);
            f16x8 af[4], bfr[4];
#pragma unroll
            for (int t = 0; t < 4; t++) {
                int row = rh * 64 + t * 16 + l15;
                af[t]  = *(const f16x8*)(Ab + ((row << 3) + sw) * 16);
                int col = ch * 64 + t * 16 + l15;
                bfr[t] = *(const f16x8*)(Bb + ((col << 3) + sw) * 16);
            }
#pragma unroll
            for (int tr = 0; tr < 4; tr++)
#pragma unroll
                for (int tc = 0; tc < 4; tc++)
                    acc[tr][tc] = __builtin_amdgcn_mfma_f32_16x16x32_f16(
                        af[tr], bfr[tc], acc[tr][tc], 0, 0, 0);
        }
        __syncthreads();
    }

    // masked att -> Cs.  att = (mask && dot != 0) ? dot : NEG
    // C/D layout per 16x16 tile: row = quad*4 + rr, col = l15
#pragma unroll
    for (int tr = 0; tr < 4; tr++) {
        int rb = rh * 64 + tr * 16 + quad * 4;
#pragma unroll
        for (int tc = 0; tc < 4; tc++) {
            int col = ch * 64 + tc * 16 + l15;
            float im = imj[col];
#pragma unroll
            for (int rr = 0; rr < 4; rr++) {
                int row = rb + rr;
                float v = acc[tr][tc][rr];
                bool keep = (tmi[row] != 0.f) && (im != 0.f) && (v != 0.f);
                u.Cs[row][col] = keep ? v : NEGV;
            }
        }
    }
    __syncthreads();

    // phase 1: row softmax over l for each (jh, n) -- all 256 threads
    {
        int jh = tid >> 7, n = tid & 127;
        const float* Crow = &u.Cs[n][jh * 64];
        float m = -INFINITY;
        for (int l = 0; l < LL; l++) m = fmaxf(m, Crow[l]);
        float ssum = 0.f, ws = 0.f;
        for (int l = 0; l < LL; l++) {
            float v = Crow[l];
            float e = __expf(v - m);      // all-NEG row -> uniform
            ssum += e;
            ws += imj[jh * 64 + l] * e * v;
        }
        rowm[tid] = m;                    // stash for diagonal W (bit-exact)
        rowsm[tid] = ssum;
        rowred[tid] = tmi[n] * (ws / ssum);
    }
    __syncthreads();

    // phase 2: col softmax, ALL 256 threads, 2 per column (split over n-halves)
    {
        int c  = tid & 127;              // column 0..127
        int n0 = (tid >> 7) * 64;        // row half start
        float m = -INFINITY;
        for (int n = n0; n < n0 + 64; n++) m = fmaxf(m, u.Cs[n][c]);
        colm[tid] = m;
        __syncthreads();
        m = fmaxf(colm[tid], colm[tid ^ 128]);
        float ssum = 0.f, ws = 0.f;
        for (int n = n0; n < n0 + 64; n++) {
            float v = u.Cs[n][c];
            float e = __expf(v - m);
            ssum += e;
            ws += tmi[n] * e * v;
        }
        colp1[tid] = ssum;
        colp2[tid] = ws;
    }
    __syncthreads();
    if (tid < NN) {
        float ssum = colp1[tid] + colp1[tid + 128];
        float ws   = colp2[tid] + colp2[tid + 128];
        colred[tid] = imj[tid] * (ws / ssum);
    }

    // diagonal W (32/2048 blocks): Wh[i][n][l] = fp16(exp(vm - m)/ssum),
    // reusing phase-1 stats (bit-exact P, then RTN to fp16).
    if (jj == (i >> 1) && tid < NN) {
        int jh = i & 1;
        int n = tid;
        float m   = rowm[jh * 128 + n];
        float inv = 1.f / rowsm[jh * 128 + n];
        const float* Crow = &u.Cs[n][jh * 64];
        unsigned short* Wb = Wh + (size_t)i * NN * LL + (size_t)n * LL;
        for (int l = 0; l < LL; l++) {
            _Float16 h = (_Float16)(__expf(Crow[l] - m) * inv);
            Wb[l] = __builtin_bit_cast(unsigned short, h);
        }
    }
    __syncthreads();

    // S[i][j0+jh] = (sum_n rowred + sum_l colred) / N   (waves 0,1)
    if (tid < NN) {
        int jh = tid >> 6, t = tid & 63;
        float p = rowred[jh * 128 + t] + rowred[jh * 128 + 64 + t] + colred[jh * 64 + t];
#pragma unroll
        for (int off = 32; off; off >>= 1) p += __shfl_down(p, off);
        if (t == 0) S[i * BSZ + j0 + jh] = p / (float)NN;
    }
}

// ---------------------------------------------------------------------------
// Kernel 2: MFMA i2s.  out[b,n,d] = sum_l P[l,n] * img[l,d] as f16 GEMM
// (M=128 n, N=768 d, K=64 l) per b.  Grid (64, 6): block = 128 n x 128 d;
// 4 waves = 2 n-halves x 2 d-halves, 64x64/wave = acc[4][4].  A = Wh[n][l],
// B = BT[d][l]: both k-contiguous -> direct global f16x8 loads, NO LDS.
// k_loss fused into the tail of block (0,0).  Verified R12. FROZEN.
// ---------------------------------------------------------------------------
__global__ __launch_bounds__(256) void k_i2s(
    const unsigned short* __restrict__ Wh, const unsigned short* __restrict__ BT,
    const float* __restrict__ S, float* __restrict__ out)
{
    const int b   = blockIdx.x;
    const int dc  = blockIdx.y;              // 0..5
    const int tid = threadIdx.x;
    const int wave = tid >> 6, lane = tid & 63;
    const int quad = lane >> 4, l15 = lane & 15;
    const int nb = (wave >> 1) * 64;                 // n-base (0 or 64)
    const int db = dc * 128 + (wave & 1) * 64;       // d-base

    const unsigned short* Wb = Wh + (size_t)b * NN * LL;
    const unsigned short* Bb = BT + (size_t)b * DD * LL;

    f32x4 acc[4][4];
    const f32x4 zf = {0.f, 0.f, 0.f, 0.f};
#pragma unroll
    for (int tn = 0; tn < 4; tn++)
#pragma unroll
        for (int td = 0; td < 4; td++) acc[tn][td] = zf;

#pragma unroll
    for (int s = 0; s < 2; s++) {
        f16x8 af[4], bf[4];
#pragma unroll
        for (int t = 0; t < 4; t++) {
            af[t] = *(const f16x8*)(Wb + (size_t)(nb + t * 16 + l15) * LL + s * 32 + quad * 8);
            bf[t] = *(const f16x8*)(Bb + (size_t)(db + t * 16 + l15) * LL + s * 32 + quad * 8);
        }
#pragma unroll
        for (int tn = 0; tn < 4; tn++)
#pragma unroll
            for (int td = 0; td < 4; td++)
                acc[tn][td] = __builtin_amdgcn_mfma_f32_16x16x32_f16(
                    af[tn], bf[td], acc[tn][td], 0, 0, 0);
    }

    // C/D: row(n) = quad*4 + rr, col(d) = l15 — coalesced 16-lane stores
    float* ob = out + 1 + (size_t)b * NN * DD;
#pragma unroll
    for (int tn = 0; tn < 4; tn++)
#pragma unroll
        for (int td = 0; td < 4; td++)
#pragma unroll
            for (int rr = 0; rr < 4; rr++) {
                int n = nb + tn * 16 + quad * 4 + rr;
                int d = db + td * 16 + l15;
                ob[(size_t)n * DD + d] = acc[tn][td][rr];
            }

    // fused loss: loss = -sum_i( 2*S[i,i] - lse_row_i(S) - lse_col_i(S) ) / B
    if (blockIdx.x == 0 && blockIdx.y == 0 && tid < 64) {
        const int t = tid;  // 0..63
        float diag = S[t * BSZ + t];
        float m1 = -INFINITY, m2 = -INFINITY;
        for (int jj = 0; jj < BSZ; jj++) {
            m1 = fmaxf(m1, S[t * BSZ + jj]);
            m2 = fmaxf(m2, S[jj * BSZ + t]);
        }
        float s1 = 0.f, s2 = 0.f;
        for (int jj = 0; jj < BSZ; jj++) {
            s1 += __expf(S[t * BSZ + jj] - m1);
            s2 += __expf(S[jj * BSZ + t] - m2);
        }
        float p = 2.f * diag - (m1 + logf(s1)) - (m2 + logf(s2));
#pragma unroll
        for (int off = 32; off; off >>= 1) p += __shfl_down(p, off);
        if (t == 0) out[0] = -p / (float)BSZ;
    }
}

// ---------------------------------------------------------------------------
extern "C" void kernel_launch(void* const* d_in, const int* in_sizes, int n_in,
                              void* d_out, int out_size, void* d_ws, size_t ws_size,
                              hipStream_t stream)
{
    (void)in_sizes; (void)n_in; (void)out_size; (void)ws_size;
    const float* text = (const float*)d_in[0];   // [64,128,768] fp32
    const float* img  = (const float*)d_in[1];   // [64, 64,768] fp32
    const int*   tm   = (const int*)d_in[2];     // [64,128] int32
    const int*   im   = (const int*)d_in[3];     // [64, 64] int32
    float* out = (float*)d_out;                  // [1 + 64*128*768] fp32

    // workspace layout (bytes), ~26 MB:
    //   A  [0, 12.58M)         text fp16 [i][n][d]
    //   B  [12.58M, 18.87M)    image fp16 [b][l][d]
    //   S  at 18874368         16 KB
    //   Wh at 18890752         1.05 MB fp16 P^T [i][n][l]
    //   BT at 19939328         6.29 MB fp16 img^T [b][d][l]
    char* ws = (char*)d_ws;
    unsigned short* A  = (unsigned short*)(ws);
    unsigned short* B  = (unsigned short*)(ws + 12582912);
    float*          S  = (float*)(ws + 18874368);
    unsigned short* Wh = (unsigned short*)(ws + 18890752);
    unsigned short* BT = (unsigned short*)(ws + 19939328);

    k_prep<<<PREP_BLOCKS + TR_BLOCKS, 256, 0, stream>>>(
        (const float4*)text, (const float4*)img, (ushort4*)A, (ushort4*)B, BT);

    k_scores<<<BSZ * (BSZ / 2), 256, 0, stream>>>(A, B, tm, im, S, Wh);

    dim3 g2(BSZ, 6);
    k_i2s<<<g2, 256, 0, stream>>>(Wh, BT, S, out);
}